// Round 2
// baseline (356.274 us; speedup 1.0000x reference)
//
#include <hip/hip_runtime.h>
#include <stdint.h>

#define R 128
#define NB 64

// workspace float offsets
#define CAM0_OFF 0          // 64*128*784 = 6422528
#define CAM1_OFF 6422528    // 64*128*196 = 1605632
#define CAM2_OFF 8028160    // 64*128*49  = 401408
#define POOL0_OFF 8429568   // 1605632
#define POOL1_OFF 10035200  // 401408
#define WB_OFF    10436608  // 458752 bf16 = 229376 float slots
#define PART_OFF  10665984  // 2*64*16384 = 2097152
// total 12763136 floats ~= 48.7 MB

typedef __bf16 bf16;
typedef bf16 v8bf __attribute__((ext_vector_type(8)));
typedef float f4v __attribute__((ext_vector_type(4)));

// ---------------- prep: w fp32 -> bf16 (row-major, levels concatenated) -----
__global__ void prep_w(const float* __restrict__ w0, const float* __restrict__ w1,
                       const float* __restrict__ w2, bf16* __restrict__ wb) {
    int id = blockIdx.x * 256 + threadIdx.x;   // < 458752 exact
    float v;
    if (id < 65536)       v = w0[id];
    else if (id < 196608) v = w1[id - 65536];
    else                  v = w2[id - 196608];
    wb[id] = (bf16)v;
}

// ---------------- cam GEMM: cam[b,r,i] = sum_c w[r,c]*fmap[b,c,i] ----------
// No-LDS, no-barrier direct GEMM. flat N = b*HW + i ; per-block 128m x 64n.
// 4 waves as 2x2 (wave tile 64m x 32n). A frags straight from L2-resident
// bf16 w; B frags as 8 coalesced global dword loads + cvt.
__global__ __launch_bounds__(256) void cam_gemm(
    const float* __restrict__ f0, const float* __restrict__ f1,
    const float* __restrict__ f2, const bf16* __restrict__ wb,
    float* __restrict__ ws) {
    int bid = blockIdx.x, tid = threadIdx.x;
    int lvl, tile;
    if (bid < 49)       { lvl = 2; tile = bid; }        // l2 first (heaviest blocks)
    else if (bid < 245) { lvl = 1; tile = bid - 49; }
    else                { lvl = 0; tile = bid - 245; }
    const int C  = (lvl == 0) ? 512 : (lvl == 1) ? 1024 : 2048;
    const int HW = (lvl == 0) ? 784 : (lvl == 1) ? 196  : 49;
    const float* fmap = (lvl == 0) ? f0 : (lvl == 1) ? f1 : f2;
    const bf16*  wbl  = wb + ((lvl == 0) ? 0 : (lvl == 1) ? 65536 : 196608);
    float* cam = ws + ((lvl == 0) ? CAM0_OFF : (lvl == 1) ? CAM1_OFF : CAM2_OFF);
    const int n0 = tile * 64;

    const int lane = tid & 63, wave = tid >> 6;
    const int lm = lane & 15, q = lane >> 4;
    const int wm = (wave >> 1) * 64, wn = (wave & 1) * 32;

    // per-lane B column (n) decode, b-crossing safe
    int bv[2], iv[2], bbase[2];
#pragma unroll
    for (int sn = 0; sn < 2; ++sn) {
        int n = n0 + wn + sn * 16 + lm;
        bv[sn] = n / HW; iv[sn] = n - bv[sn] * HW;
        bbase[sn] = bv[sn] * C * HW + iv[sn] + q * 8 * HW;  // includes k-offset q*8
    }
    const bf16* arow[4];
#pragma unroll
    for (int sm = 0; sm < 4; ++sm)
        arow[sm] = wbl + (wm + sm * 16 + lm) * C + q * 8;

    f4v acc[4][2] = {};
#pragma unroll 2
    for (int kc = 0; kc < C; kc += 32) {
        v8bf af[4];
#pragma unroll
        for (int sm = 0; sm < 4; ++sm)
            af[sm] = *(const v8bf*)(arow[sm] + kc);
        v8bf bfr[2];
#pragma unroll
        for (int sn = 0; sn < 2; ++sn) {
            int base = bbase[sn] + kc * HW;
#pragma unroll
            for (int j = 0; j < 8; ++j)
                bfr[sn][j] = (bf16)fmap[base + j * HW];
        }
#pragma unroll
        for (int sm = 0; sm < 4; ++sm)
#pragma unroll
            for (int sn = 0; sn < 2; ++sn)
                acc[sm][sn] = __builtin_amdgcn_mfma_f32_16x16x32_bf16(
                    af[sm], bfr[sn], acc[sm][sn], 0, 0, 0);
    }
    // epilogue: D row = q*4+reg, col = lm
#pragma unroll
    for (int sn = 0; sn < 2; ++sn) {
        int base = (bv[sn] * R) * HW + iv[sn];
#pragma unroll
        for (int sm = 0; sm < 4; ++sm) {
#pragma unroll
            for (int reg = 0; reg < 4; ++reg) {
                int r = wm + sm * 16 + q * 4 + reg;
                cam[base + r * HW] = acc[sm][sn][reg];
            }
        }
    }
}

// ---------------- stats: embedding (mean + bias) and ddof=1 std ------------
__global__ __launch_bounds__(256) void stats_k(
    const float* __restrict__ ws, const float* __restrict__ b0,
    const float* __restrict__ b1, const float* __restrict__ b2,
    float* __restrict__ out) {
    int gw = blockIdx.x * 4 + (threadIdx.x >> 6);  // wave id, < 24576
    int lane = threadIdx.x & 63;
    int lvl = gw >> 13, row = gw & 8191;           // row = b*128 + r
    const int HW = (lvl == 0) ? 784 : (lvl == 1) ? 196 : 49;
    const float* cam = ws + ((lvl == 0) ? CAM0_OFF : (lvl == 1) ? CAM1_OFF : CAM2_OFF)
                        + (long)row * HW;
    float s = 0.f, ss = 0.f;
    for (int j = lane; j < HW; j += 64) { float v = cam[j]; s += v; ss += v * v; }
#pragma unroll
    for (int o = 32; o; o >>= 1) { s += __shfl_xor(s, o); ss += __shfl_xor(ss, o); }
    if (lane == 0) {
        const float* bias = (lvl == 0) ? b0 : (lvl == 1) ? b1 : b2;
        float mean = s / (float)HW;
        out[lvl * 8192 + row] = mean + bias[row & 127];
        float var = fmaxf(ss - s * mean, 0.f) / (float)(HW - 1);
        out[24576 + lvl * 8192 + row] = sqrtf(var);
    }
}

// ---------------- fused 2x2 avgpool + L2 row-normalize (pool0, pool1) ------
// one wave per output row. op0: cam0(784)->pool0(196); op1: cam1(196)->pool1(49)
__global__ __launch_bounds__(256) void pool_norm_k(float* __restrict__ ws) {
    int gw = blockIdx.x * 4 + (threadIdx.x >> 6);  // < 16384
    int lane = threadIdx.x & 63;
    int op = gw >> 13, row = gw & 8191;
    const float* src = ws + (op == 0 ? CAM0_OFF : CAM1_OFF)
                        + (long)row * (op == 0 ? 784 : 196);
    float* dst = ws + (op == 0 ? POOL0_OFF : POOL1_OFF)
                    + (long)row * (op == 0 ? 196 : 49);
    const int OP = op == 0 ? 196 : 49;     // pooled count
    const int OW = op == 0 ? 14 : 7;
    const int IW = op == 0 ? 28 : 14;
    float vals[4]; float ss = 0.f; int cnt = 0;
    for (int p = lane; p < OP; p += 64) {
        int oh = p / OW, ow = p - oh * OW;
        int i0 = oh * 2 * IW + ow * 2;
        float v = (src[i0] + src[i0 + 1] + src[i0 + IW] + src[i0 + IW + 1]) * 0.25f;
        vals[cnt++] = v; ss += v * v;
    }
#pragma unroll
    for (int o = 32; o; o >>= 1) ss += __shfl_xor(ss, o);
    float inv = 1.0f / fmaxf(sqrtf(ss), 1e-12f);
    cnt = 0;
    for (int p = lane; p < OP; p += 64) dst[p] = vals[cnt++] * inv;
}

// ---------------- in-place L2 normalize rows of cam1, cam2 -----------------
__global__ __launch_bounds__(256) void normscale_k(float* __restrict__ ws) {
    int gw = blockIdx.x * 4 + (threadIdx.x >> 6);  // < 16384
    int lane = threadIdx.x & 63;
    int op = gw >> 13, row = gw & 8191;
    float* p; int K;
    if (op == 0) { p = ws + CAM1_OFF + (long)row * 196; K = 196; }
    else         { p = ws + CAM2_OFF + (long)row * 49;  K = 49; }
    float ss = 0.f;
    for (int j = lane; j < K; j += 64) { float v = p[j]; ss += v * v; }
#pragma unroll
    for (int o = 32; o; o >>= 1) ss += __shfl_xor(ss, o);
    float inv = 1.0f / fmaxf(sqrtf(ss), 1e-12f);
    for (int j = lane; j < K; j += 64) p[j] *= inv;
}

// ---------------- link partials: per (link, b, m-quarter, n-half) ----------
// i-chunked staging: LDS 49*(68+36)*4 = 20384 B  (was 81.5 KB -> 1 blk/CU)
__global__ __launch_bounds__(256) void link_k(const float* __restrict__ ws,
                                              float* __restrict__ part) {
    __shared__ float hiT[49 * 68];   // [i][n] pad 64->68
    __shared__ float loT[49 * 36];   // [i][m] pad 32->36
    int bid = blockIdx.x, tid = threadIdx.x;
    int lk = bid >> 9, rem = bid & 511;
    int b = rem >> 3, mq = (rem >> 1) & 3, nh = rem & 1;
    const int K = lk ? 49 : 196;
    const float* lo = ws + (lk ? POOL1_OFF : POOL0_OFF) + (long)(b * 128 + mq * 32) * K;
    const float* hi = ws + (lk ? CAM2_OFF : CAM1_OFF) + (long)(b * 128 + nh * 64) * K;
    int tm = tid >> 5, tn = tid & 31;
    int m0 = tm * 4, n0 = tn * 2;
    float a0x = 0, a0y = 0, a1x = 0, a1y = 0, a2x = 0, a2y = 0, a3x = 0, a3y = 0;
    for (int ic = 0; ic < K; ic += 49) {
        for (int idx = tid; idx < 64 * 49; idx += 256) {
            int nr = idx / 49, i = idx - nr * 49;
            hiT[i * 68 + nr] = hi[nr * K + ic + i];
        }
        for (int idx = tid; idx < 32 * 49; idx += 256) {
            int mr = idx / 49, i = idx - mr * 49;
            loT[i * 36 + mr] = lo[mr * K + ic + i];
        }
        __syncthreads();
#pragma unroll 7
        for (int i = 0; i < 49; ++i) {
            float4 lv = *(const float4*)&loT[i * 36 + m0];
            float2 hv = *(const float2*)&hiT[i * 68 + n0];
            a0x += lv.x * hv.x; a0y += lv.x * hv.y;
            a1x += lv.y * hv.x; a1y += lv.y * hv.y;
            a2x += lv.z * hv.x; a2y += lv.z * hv.y;
            a3x += lv.w * hv.x; a3y += lv.w * hv.y;
        }
        __syncthreads();
    }
    float* dst = part + lk * 1048576 + b * 16384 + (mq * 32 + m0) * 128 + nh * 64 + n0;
    dst[0] = a0x; dst[1] = a0y;
    dst[128] = a1x; dst[129] = a1y;
    dst[256] = a2x; dst[257] = a2y;
    dst[384] = a3x; dst[385] = a3y;
}

// ---------------- reduce partials over b, scale by 1/B ---------------------
__global__ void linkred_k(const float* __restrict__ part, float* __restrict__ out) {
    int id = blockIdx.x * 256 + threadIdx.x;  // < 32768
    int lk = id >> 14, mn = id & 16383;
    const float* p = part + lk * 1048576 + mn;
    float s = 0.f;
#pragma unroll 8
    for (int b = 0; b < 64; ++b) s += p[b * 16384];
    out[49152 + lk * 16384 + mn] = s * (1.0f / 64.0f);
}

extern "C" void kernel_launch(void* const* d_in, const int* in_sizes, int n_in,
                              void* d_out, int out_size, void* d_ws, size_t ws_size,
                              hipStream_t stream) {
    const float* f0 = (const float*)d_in[0];
    const float* w0 = (const float*)d_in[1];
    const float* b0 = (const float*)d_in[2];
    const float* f1 = (const float*)d_in[3];
    const float* w1 = (const float*)d_in[4];
    const float* b1 = (const float*)d_in[5];
    const float* f2 = (const float*)d_in[6];
    const float* w2 = (const float*)d_in[7];
    const float* b2 = (const float*)d_in[8];
    float* ws = (float*)d_ws;
    float* out = (float*)d_out;
    bf16* wb = (bf16*)(ws + WB_OFF);

    prep_w<<<1792, 256, 0, stream>>>(w0, w1, w2, wb);
    cam_gemm<<<1029, 256, 0, stream>>>(f0, f1, f2, wb, ws);
    stats_k<<<6144, 256, 0, stream>>>(ws, b0, b1, b2, out);
    pool_norm_k<<<4096, 256, 0, stream>>>(ws);     // reads raw cam1 (before normscale)
    normscale_k<<<4096, 256, 0, stream>>>(ws);
    link_k<<<1024, 256, 0, stream>>>(ws, ws + PART_OFF);
    linkred_k<<<128, 256, 0, stream>>>(ws + PART_OFF, out);
}

// Round 3
// 356.169 us; speedup vs baseline: 1.0003x; 1.0003x over previous
//
#include <hip/hip_runtime.h>
#include <stdint.h>

#define R 128
#define NB 64

// workspace float offsets
#define CAM0_OFF 0          // 64*128*784 = 6422528
#define CAM1_OFF 6422528    // 64*128*196 = 1605632
#define CAM2_OFF 8028160    // 64*128*49  = 401408
#define POOL0_OFF 8429568   // 1605632
#define POOL1_OFF 10035200  // 401408
#define WB_OFF    10436608  // 458752 bf16 = 229376 float slots
#define PART_OFF  10665984  // 2*64*16384 = 2097152
#define NORM_OFF  12763136  // 2*8192 inv-norms (cam1 rows, cam2 rows)
// total 12779520 floats ~= 48.8 MiB

typedef __bf16 bf16;
typedef bf16 v2bf __attribute__((ext_vector_type(2)));
typedef bf16 v8bf __attribute__((ext_vector_type(8)));
typedef float f4v __attribute__((ext_vector_type(4)));

// ---------------- prep: w fp32 -> bf16 (row-major, levels concatenated) -----
__global__ void prep_w(const float* __restrict__ w0, const float* __restrict__ w1,
                       const float* __restrict__ w2, bf16* __restrict__ wb) {
    int id = blockIdx.x * 256 + threadIdx.x;   // < 458752 exact
    float v;
    if (id < 65536)       v = w0[id];
    else if (id < 196608) v = w1[id - 65536];
    else                  v = w2[id - 196608];
    wb[id] = (bf16)v;
}

// ---------------- cam GEMM: cam[b,r,i] = sum_c w[r,c]*fmap[b,c,i] ----------
// Per-b aligned N-tiles (BN=64, no b-crossing). B staged to LDS transposed
// [n][k] bf16 (XOR-swizzled 16B groups), frag read = 1 ds_read_b128.
// A direct from L2-resident bf16 w. BM=128, BK=64; 4 waves as 2x2.
__global__ __launch_bounds__(256) void cam_gemm(
    const float* __restrict__ f0, const float* __restrict__ f1,
    const float* __restrict__ f2, const bf16* __restrict__ wb,
    float* __restrict__ ws) {
    __shared__ bf16 ldsB[64 * 72];   // row stride 72 bf16 = 144 B (16B mult)

    int bid = blockIdx.x, tid = threadIdx.x;
    int lvl, b, i0;
    if (bid < 64)       { lvl = 2; b = bid; i0 = 0; }              // heavy first
    else if (bid < 320) { int t = bid - 64; lvl = 1; b = t >> 2;
                          int ti = t & 3; i0 = ti < 3 ? ti * 64 : 132; }
    else                { int t = bid - 320; lvl = 0; b = t / 13;
                          int ti = t - b * 13; i0 = ti < 12 ? ti * 64 : 720; }
    const int C  = (lvl == 0) ? 512 : (lvl == 1) ? 1024 : 2048;
    const int HW = (lvl == 0) ? 784 : (lvl == 1) ? 196  : 49;
    const float* fmap = (lvl == 0) ? f0 : (lvl == 1) ? f1 : f2;
    const bf16*  wbl  = wb + ((lvl == 0) ? 0 : (lvl == 1) ? 65536 : 196608);
    float* cam = ws + ((lvl == 0) ? CAM0_OFF : (lvl == 1) ? CAM1_OFF : CAM2_OFF);

    // staging decode: 2 units/thread; unit covers 2 k-rows x 4 i
    int ku2[2], i4u[2], gbase[2], ldsd[2][4];
#pragma unroll
    for (int un = 0; un < 2; ++un) {
        int u = un * 256 + tid;           // 0..511
        int d = u >> 4;                   // k-pair id 0..31 (dword in row)
        ku2[un] = d * 2;
        int g = u & 15; i4u[un] = g * 4;
        gbase[un] = b * C * HW + ku2[un] * HW + i0 + i4u[un];
#pragma unroll
        for (int e = 0; e < 4; ++e) {
            int i = i4u[un] + e;          // LDS row (n-local)
            int grp = (d >> 2) ^ ((i >> 3) & 7);
            ldsd[un][e] = i * 72 + grp * 8 + (d & 3) * 2;   // bf16 units
        }
    }
    const int lane = tid & 63, wave = tid >> 6;
    const int lm = lane & 15, q = lane >> 4;
    const int wm = (wave >> 1) * 64, wn = (wave & 1) * 32;
    int irow[2], ixor[2];
#pragma unroll
    for (int sn = 0; sn < 2; ++sn) {
        irow[sn] = wn + sn * 16 + lm;
        ixor[sn] = (irow[sn] >> 3) & 7;
    }
    const bf16* arow[4];
#pragma unroll
    for (int sm = 0; sm < 4; ++sm)
        arow[sm] = wbl + (wm + sm * 16 + lm) * C + q * 8;

    f4v acc[4][2] = {};
    for (int kc = 0; kc < C; kc += 64) {
        // ---- stage B tile [64k x 64n] -> LDS [n][k] bf16 ----
#pragma unroll
        for (int un = 0; un < 2; ++un) {
            float4 r0, r1;
            if (HW != 49) {
                const float* p = fmap + gbase[un] + kc * HW;
                r0 = *(const float4*)p;
                r1 = *(const float4*)(p + HW);
            } else {
                const float* p = fmap + b * C * 49 + (kc + ku2[un]) * 49;
                int i4 = i4u[un];
                r0.x = p[min(i4 + 0, 48)]; r0.y = p[min(i4 + 1, 48)];
                r0.z = p[min(i4 + 2, 48)]; r0.w = p[min(i4 + 3, 48)];
                r1.x = p[49 + min(i4 + 0, 48)]; r1.y = p[49 + min(i4 + 1, 48)];
                r1.z = p[49 + min(i4 + 2, 48)]; r1.w = p[49 + min(i4 + 3, 48)];
            }
            v2bf t0 = { (bf16)r0.x, (bf16)r1.x };
            v2bf t1 = { (bf16)r0.y, (bf16)r1.y };
            v2bf t2 = { (bf16)r0.z, (bf16)r1.z };
            v2bf t3 = { (bf16)r0.w, (bf16)r1.w };
            *(v2bf*)&ldsB[ldsd[un][0]] = t0;
            *(v2bf*)&ldsB[ldsd[un][1]] = t1;
            *(v2bf*)&ldsB[ldsd[un][2]] = t2;
            *(v2bf*)&ldsB[ldsd[un][3]] = t3;
        }
        __syncthreads();
        // ---- compute ----
#pragma unroll
        for (int ks = 0; ks < 64; ks += 32) {
            v8bf af[4];
#pragma unroll
            for (int sm = 0; sm < 4; ++sm)
                af[sm] = *(const v8bf*)(arow[sm] + kc + ks);
            v8bf bfr[2];
#pragma unroll
            for (int sn = 0; sn < 2; ++sn) {
                int grp = (q + ((ks >> 5) << 2)) ^ ixor[sn];
                bfr[sn] = *(const v8bf*)&ldsB[irow[sn] * 72 + grp * 8];
            }
#pragma unroll
            for (int sm = 0; sm < 4; ++sm)
#pragma unroll
                for (int sn = 0; sn < 2; ++sn)
                    acc[sm][sn] = __builtin_amdgcn_mfma_f32_16x16x32_bf16(
                        af[sm], bfr[sn], acc[sm][sn], 0, 0, 0);
        }
        __syncthreads();
    }
    // epilogue: D row = q*4+reg, col = lm
#pragma unroll
    for (int sn = 0; sn < 2; ++sn) {
        int i_n = i0 + irow[sn];
        if (i_n < HW) {
            int base = (b * R) * HW + i_n;
#pragma unroll
            for (int sm = 0; sm < 4; ++sm) {
#pragma unroll
                for (int reg = 0; reg < 4; ++reg) {
                    int r = wm + sm * 16 + q * 4 + reg;
                    cam[base + r * HW] = acc[sm][sn][reg];
                }
            }
        }
    }
}

// ---------------- fused post: stats (+inv-norms) and pool+normalize --------
// waves 0..24575: stats row (lvl,row); lvl 1/2 also emit row inv-norm.
// waves 24576..40959: pool op (pool0 from cam0, pool1 from cam1), normalized.
__global__ __launch_bounds__(256) void post_k(
    float* __restrict__ ws, const float* __restrict__ b0,
    const float* __restrict__ b1, const float* __restrict__ b2,
    float* __restrict__ out) {
    int gw = blockIdx.x * 4 + (threadIdx.x >> 6);  // < 40960
    int lane = threadIdx.x & 63;
    if (gw < 24576) {
        int lvl = gw >> 13, row = gw & 8191;       // row = b*128 + r
        const int HW = (lvl == 0) ? 784 : (lvl == 1) ? 196 : 49;
        const float* cam = ws + ((lvl == 0) ? CAM0_OFF : (lvl == 1) ? CAM1_OFF : CAM2_OFF)
                            + (long)row * HW;
        float s = 0.f, ss = 0.f;
        for (int j = lane; j < HW; j += 64) { float v = cam[j]; s += v; ss += v * v; }
#pragma unroll
        for (int o = 32; o; o >>= 1) { s += __shfl_xor(s, o); ss += __shfl_xor(ss, o); }
        if (lane == 0) {
            const float* bias = (lvl == 0) ? b0 : (lvl == 1) ? b1 : b2;
            float mean = s / (float)HW;
            out[lvl * 8192 + row] = mean + bias[row & 127];
            float var = fmaxf(ss - s * mean, 0.f) / (float)(HW - 1);
            out[24576 + lvl * 8192 + row] = sqrtf(var);
            if (lvl >= 1)
                ws[NORM_OFF + (lvl - 1) * 8192 + row] = 1.0f / fmaxf(sqrtf(ss), 1e-12f);
        }
    } else {
        int p = gw - 24576;
        int op = p >> 13, row = p & 8191;
        const float* src = ws + (op == 0 ? CAM0_OFF : CAM1_OFF)
                            + (long)row * (op == 0 ? 784 : 196);
        float* dst = ws + (op == 0 ? POOL0_OFF : POOL1_OFF)
                        + (long)row * (op == 0 ? 196 : 49);
        const int OP = op == 0 ? 196 : 49;
        const int OW = op == 0 ? 14 : 7;
        const int IW = op == 0 ? 28 : 14;
        float vals[4]; float ss = 0.f; int cnt = 0;
        for (int pp = lane; pp < OP; pp += 64) {
            int oh = pp / OW, ow = pp - oh * OW;
            int i0 = oh * 2 * IW + ow * 2;
            float v = (src[i0] + src[i0 + 1] + src[i0 + IW] + src[i0 + IW + 1]) * 0.25f;
            vals[cnt++] = v; ss += v * v;
        }
#pragma unroll
        for (int o = 32; o; o >>= 1) ss += __shfl_xor(ss, o);
        float inv = 1.0f / fmaxf(sqrtf(ss), 1e-12f);
        cnt = 0;
        for (int pp = lane; pp < OP; pp += 64) dst[pp] = vals[cnt++] * inv;
    }
}

// ---------------- link partials: per (link, b, m-quarter, n-half) ----------
// lo = normalized pool rows; hi = RAW cam rows, scaled by inv-norm at store.
__global__ __launch_bounds__(256) void link_k(const float* __restrict__ ws,
                                              float* __restrict__ part) {
    __shared__ float hiT[49 * 68];   // [i][n] pad 64->68
    __shared__ float loT[49 * 36];   // [i][m] pad 32->36
    int bid = blockIdx.x, tid = threadIdx.x;
    int lk = bid >> 9, rem = bid & 511;
    int b = rem >> 3, mq = (rem >> 1) & 3, nh = rem & 1;
    const int K = lk ? 49 : 196;
    const float* lo = ws + (lk ? POOL1_OFF : POOL0_OFF) + (long)(b * 128 + mq * 32) * K;
    const float* hi = ws + (lk ? CAM2_OFF : CAM1_OFF) + (long)(b * 128 + nh * 64) * K;
    const float* nrm = ws + NORM_OFF + lk * 8192 + b * 128 + nh * 64;
    int tm = tid >> 5, tn = tid & 31;
    int m0 = tm * 4, n0 = tn * 2;
    float a0x = 0, a0y = 0, a1x = 0, a1y = 0, a2x = 0, a2y = 0, a3x = 0, a3y = 0;
    for (int ic = 0; ic < K; ic += 49) {
        for (int idx = tid; idx < 64 * 49; idx += 256) {
            int nr = idx / 49, i = idx - nr * 49;
            hiT[i * 68 + nr] = hi[nr * K + ic + i];
        }
        for (int idx = tid; idx < 32 * 49; idx += 256) {
            int mr = idx / 49, i = idx - mr * 49;
            loT[i * 36 + mr] = lo[mr * K + ic + i];
        }
        __syncthreads();
#pragma unroll 7
        for (int i = 0; i < 49; ++i) {
            float4 lv = *(const float4*)&loT[i * 36 + m0];
            float2 hv = *(const float2*)&hiT[i * 68 + n0];
            a0x += lv.x * hv.x; a0y += lv.x * hv.y;
            a1x += lv.y * hv.x; a1y += lv.y * hv.y;
            a2x += lv.z * hv.x; a2y += lv.z * hv.y;
            a3x += lv.w * hv.x; a3y += lv.w * hv.y;
        }
        __syncthreads();
    }
    float sh0 = nrm[n0], sh1 = nrm[n0 + 1];
    float* dst = part + lk * 1048576 + b * 16384 + (mq * 32 + m0) * 128 + nh * 64 + n0;
    dst[0] = a0x * sh0;   dst[1] = a0y * sh1;
    dst[128] = a1x * sh0; dst[129] = a1y * sh1;
    dst[256] = a2x * sh0; dst[257] = a2y * sh1;
    dst[384] = a3x * sh0; dst[385] = a3y * sh1;
}

// ---------------- reduce partials over b, scale by 1/B ---------------------
__global__ void linkred_k(const float* __restrict__ part, float* __restrict__ out) {
    int id = blockIdx.x * 256 + threadIdx.x;  // < 32768
    int lk = id >> 14, mn = id & 16383;
    const float* p = part + lk * 1048576 + mn;
    float s = 0.f;
#pragma unroll 8
    for (int b = 0; b < 64; ++b) s += p[b * 16384];
    out[49152 + lk * 16384 + mn] = s * (1.0f / 64.0f);
}

extern "C" void kernel_launch(void* const* d_in, const int* in_sizes, int n_in,
                              void* d_out, int out_size, void* d_ws, size_t ws_size,
                              hipStream_t stream) {
    const float* f0 = (const float*)d_in[0];
    const float* w0 = (const float*)d_in[1];
    const float* b0 = (const float*)d_in[2];
    const float* f1 = (const float*)d_in[3];
    const float* w1 = (const float*)d_in[4];
    const float* b1 = (const float*)d_in[5];
    const float* f2 = (const float*)d_in[6];
    const float* w2 = (const float*)d_in[7];
    const float* b2 = (const float*)d_in[8];
    float* ws = (float*)d_ws;
    float* out = (float*)d_out;
    bf16* wb = (bf16*)(ws + WB_OFF);

    prep_w<<<1792, 256, 0, stream>>>(w0, w1, w2, wb);
    cam_gemm<<<1152, 256, 0, stream>>>(f0, f1, f2, wb, ws);
    post_k<<<10240, 256, 0, stream>>>(ws, b0, b1, b2, out);
    link_k<<<1024, 256, 0, stream>>>(ws, ws + PART_OFF);
    linkred_k<<<128, 256, 0, stream>>>(ws + PART_OFF, out);
}

// Round 4
// 330.835 us; speedup vs baseline: 1.0769x; 1.0766x over previous
//
#include <hip/hip_runtime.h>
#include <stdint.h>

#define R 128
#define NB 64

// workspace float offsets
#define CAM0_OFF 0          // 64*128*784 = 6422528
#define CAM1_OFF 6422528    // 64*128*196 = 1605632
#define CAM2_OFF 8028160    // 64*128*49  = 401408
#define POOL0_OFF 8429568   // 1605632
#define POOL1_OFF 10035200  // 401408
#define WB_OFF    10436608  // 458752 bf16 = 229376 float slots
#define PART_OFF  10665984  // 2*64*16384 = 2097152
#define NORM_OFF  12763136  // 2*8192 inv-norms (cam1 rows, cam2 rows)
// total 12779520 floats ~= 48.8 MiB

typedef __bf16 bf16;
typedef bf16 v2bf __attribute__((ext_vector_type(2)));
typedef bf16 v8bf __attribute__((ext_vector_type(8)));
typedef float f4v __attribute__((ext_vector_type(4)));

#define ASM_BARRIER() asm volatile("s_waitcnt lgkmcnt(0)\n\ts_barrier" ::: "memory")

// ---------------- prep: w fp32 -> bf16 (row-major, levels concatenated) -----
__global__ void prep_w(const float* __restrict__ w0, const float* __restrict__ w1,
                       const float* __restrict__ w2, bf16* __restrict__ wb) {
    int id = blockIdx.x * 256 + threadIdx.x;   // < 458752 exact
    float v;
    if (id < 65536)       v = w0[id];
    else if (id < 196608) v = w1[id - 65536];
    else                  v = w2[id - 196608];
    wb[id] = (bf16)v;
}

// ---------------- cam GEMM: cam[b,r,i] = sum_c w[r,c]*fmap[b,c,i] ----------
// Software-pipelined: next B-tile prefetched to registers during compute;
// raw s_barrier (lgkm only) keeps prefetch loads in flight across barriers.
// B staged to LDS transposed [n][k] bf16, XOR-swizzled; A direct from L2.
__global__ __launch_bounds__(256) void cam_gemm(
    const float* __restrict__ f0, const float* __restrict__ f1,
    const float* __restrict__ f2, const bf16* __restrict__ wb,
    float* __restrict__ ws) {
    __shared__ bf16 ldsB[64 * 72];   // row stride 72 bf16 = 144 B

    int bid = blockIdx.x, tid = threadIdx.x;
    int lvl, b, i0;
    if (bid < 64)       { lvl = 2; b = bid; i0 = 0; }              // heavy first
    else if (bid < 320) { int t = bid - 64; lvl = 1; b = t >> 2;
                          int ti = t & 3; i0 = ti < 3 ? ti * 64 : 132; }
    else                { int t = bid - 320; lvl = 0; b = t / 13;
                          int ti = t - b * 13; i0 = ti < 12 ? ti * 64 : 720; }
    const int C  = (lvl == 0) ? 512 : (lvl == 1) ? 1024 : 2048;
    const int HW = (lvl == 0) ? 784 : (lvl == 1) ? 196  : 49;
    const float* fmap = (lvl == 0) ? f0 : (lvl == 1) ? f1 : f2;
    const bf16*  wbl  = wb + ((lvl == 0) ? 0 : (lvl == 1) ? 65536 : 196608);
    float* cam = ws + ((lvl == 0) ? CAM0_OFF : (lvl == 1) ? CAM1_OFF : CAM2_OFF);

    // staging decode: 2 units/thread; unit covers 2 k-rows x 4 i
    int ku2[2], i4u[2], gbase[2], ldsd[2][4];
#pragma unroll
    for (int un = 0; un < 2; ++un) {
        int u = un * 256 + tid;           // 0..511
        int d = u >> 4;                   // k-pair id 0..31
        ku2[un] = d * 2;
        int g = u & 15; i4u[un] = g * 4;
        gbase[un] = b * C * HW + ku2[un] * HW + i0 + i4u[un];
#pragma unroll
        for (int e = 0; e < 4; ++e) {
            int i = i4u[un] + e;          // LDS row (n-local)
            int grp = (d >> 2) ^ ((i >> 3) & 7);
            ldsd[un][e] = i * 72 + grp * 8 + (d & 3) * 2;   // bf16 units
        }
    }
    const int lane = tid & 63, wave = tid >> 6;
    const int lm = lane & 15, q = lane >> 4;
    const int wm = (wave >> 1) * 64, wn = (wave & 1) * 32;
    int irow[2], ixor[2];
#pragma unroll
    for (int sn = 0; sn < 2; ++sn) {
        irow[sn] = wn + sn * 16 + lm;
        ixor[sn] = (irow[sn] >> 3) & 7;
    }
    const bf16* arow[4];
#pragma unroll
    for (int sm = 0; sm < 4; ++sm)
        arow[sm] = wbl + (wm + sm * 16 + lm) * C + q * 8;

    auto load_tile = [&](int kc, float4 (&r)[2][2]) {
        if (HW != 49) {
#pragma unroll
            for (int un = 0; un < 2; ++un) {
                const float* p = fmap + gbase[un] + kc * HW;
                r[un][0] = *(const float4*)p;
                r[un][1] = *(const float4*)(p + HW);
            }
        } else {
#pragma unroll
            for (int un = 0; un < 2; ++un) {
                const float* p = fmap + b * C * 49 + (kc + ku2[un]) * 49;
                int i4 = i4u[un];
                r[un][0].x = p[min(i4 + 0, 48)]; r[un][0].y = p[min(i4 + 1, 48)];
                r[un][0].z = p[min(i4 + 2, 48)]; r[un][0].w = p[min(i4 + 3, 48)];
                r[un][1].x = p[49 + min(i4 + 0, 48)]; r[un][1].y = p[49 + min(i4 + 1, 48)];
                r[un][1].z = p[49 + min(i4 + 2, 48)]; r[un][1].w = p[49 + min(i4 + 3, 48)];
            }
        }
    };

    f4v acc[4][2] = {};
    float4 pr[2][2];
    load_tile(0, pr);
    for (int kc = 0; kc < C; kc += 64) {
        // ---- write prefetched tile -> LDS (cvt bf16, transposed) ----
#pragma unroll
        for (int un = 0; un < 2; ++un) {
            v2bf t0 = { (bf16)pr[un][0].x, (bf16)pr[un][1].x };
            v2bf t1 = { (bf16)pr[un][0].y, (bf16)pr[un][1].y };
            v2bf t2 = { (bf16)pr[un][0].z, (bf16)pr[un][1].z };
            v2bf t3 = { (bf16)pr[un][0].w, (bf16)pr[un][1].w };
            *(v2bf*)&ldsB[ldsd[un][0]] = t0;
            *(v2bf*)&ldsB[ldsd[un][1]] = t1;
            *(v2bf*)&ldsB[ldsd[un][2]] = t2;
            *(v2bf*)&ldsB[ldsd[un][3]] = t3;
        }
        ASM_BARRIER();
        // ---- prefetch next tile (stays in flight through compute) ----
        if (kc + 64 < C) load_tile(kc + 64, pr);
        // ---- compute ----
#pragma unroll
        for (int ks = 0; ks < 64; ks += 32) {
            v8bf af[4];
#pragma unroll
            for (int sm = 0; sm < 4; ++sm)
                af[sm] = *(const v8bf*)(arow[sm] + kc + ks);
            v8bf bfr[2];
#pragma unroll
            for (int sn = 0; sn < 2; ++sn) {
                int grp = (q + ((ks >> 5) << 2)) ^ ixor[sn];
                bfr[sn] = *(const v8bf*)&ldsB[irow[sn] * 72 + grp * 8];
            }
#pragma unroll
            for (int sm = 0; sm < 4; ++sm)
#pragma unroll
                for (int sn = 0; sn < 2; ++sn)
                    acc[sm][sn] = __builtin_amdgcn_mfma_f32_16x16x32_bf16(
                        af[sm], bfr[sn], acc[sm][sn], 0, 0, 0);
        }
        ASM_BARRIER();
    }
    // epilogue: D row = q*4+reg, col = lm
#pragma unroll
    for (int sn = 0; sn < 2; ++sn) {
        int i_n = i0 + irow[sn];
        if (i_n < HW) {
            int base = (b * R) * HW + i_n;
#pragma unroll
            for (int sm = 0; sm < 4; ++sm) {
#pragma unroll
                for (int reg = 0; reg < 4; ++reg) {
                    int r = wm + sm * 16 + q * 4 + reg;
                    cam[base + r * HW] = acc[sm][sn][reg];
                }
            }
        }
    }
}

// ---------------- fused post: stats + inv-norms + pooling (single cam read) -
// one wave per (lvl,row). lvl0/1 also pool (via per-wave LDS row) + normalize.
__global__ __launch_bounds__(256) void post_k(
    float* __restrict__ ws, const float* __restrict__ b0,
    const float* __restrict__ b1, const float* __restrict__ b2,
    float* __restrict__ out) {
    __shared__ float plds[4 * 784];
    int gw = blockIdx.x * 4 + (threadIdx.x >> 6);  // < 24576
    int lane = threadIdx.x & 63;
    float* myl = plds + (threadIdx.x >> 6) * 784;
    int lvl = gw >> 13, row = gw & 8191;           // row = b*128 + r
    const int HW = (lvl == 0) ? 784 : (lvl == 1) ? 196 : 49;
    const float* cam = ws + ((lvl == 0) ? CAM0_OFF : (lvl == 1) ? CAM1_OFF : CAM2_OFF)
                        + (long)row * HW;
    float s = 0.f, ss = 0.f;
    for (int j = lane; j < HW; j += 64) {
        float v = cam[j]; s += v; ss += v * v; myl[j] = v;
    }
#pragma unroll
    for (int o = 32; o; o >>= 1) { s += __shfl_xor(s, o); ss += __shfl_xor(ss, o); }
    if (lane == 0) {
        const float* bias = (lvl == 0) ? b0 : (lvl == 1) ? b1 : b2;
        float mean = s / (float)HW;
        out[lvl * 8192 + row] = mean + bias[row & 127];
        float var = fmaxf(ss - s * mean, 0.f) / (float)(HW - 1);
        out[24576 + lvl * 8192 + row] = sqrtf(var);
        if (lvl >= 1)
            ws[NORM_OFF + (lvl - 1) * 8192 + row] = 1.0f / fmaxf(sqrtf(ss), 1e-12f);
    }
    if (lvl <= 1) {
        const int OP = (lvl == 0) ? 196 : 49;
        const int OW = (lvl == 0) ? 14 : 7;
        const int IW = (lvl == 0) ? 28 : 14;
        float vals[4]; float ssp = 0.f; int cnt = 0;
        for (int p = lane; p < OP; p += 64) {
            int oh = p / OW, ow = p - oh * OW;
            int i0 = oh * 2 * IW + ow * 2;
            float v = (myl[i0] + myl[i0 + 1] + myl[i0 + IW] + myl[i0 + IW + 1]) * 0.25f;
            vals[cnt++] = v; ssp += v * v;
        }
#pragma unroll
        for (int o = 32; o; o >>= 1) ssp += __shfl_xor(ssp, o);
        float inv = 1.0f / fmaxf(sqrtf(ssp), 1e-12f);
        float* dst = ws + ((lvl == 0) ? POOL0_OFF : POOL1_OFF) + (long)row * OP;
        cnt = 0;
        for (int p = lane; p < OP; p += 64) dst[p] = vals[cnt++] * inv;
    }
}

// ---------------- link via MFMA, direct global frags (contraction over i) ---
__device__ inline v8bf load_frag8(const float* __restrict__ row, int k0, int K) {
    v8bf f;
    if (k0 + 8 <= K && (K & 3) == 0) {
        float4 a = *(const float4*)(row + k0);
        float4 c = *(const float4*)(row + k0 + 4);
        f[0] = (bf16)a.x; f[1] = (bf16)a.y; f[2] = (bf16)a.z; f[3] = (bf16)a.w;
        f[4] = (bf16)c.x; f[5] = (bf16)c.y; f[6] = (bf16)c.z; f[7] = (bf16)c.w;
    } else {
#pragma unroll
        for (int j = 0; j < 8; ++j)
            f[j] = (k0 + j < K) ? (bf16)row[k0 + j] : (bf16)0.f;
    }
    return f;
}

// one block per (lk, b): D[m][n] = sum_i lo[b,m,i]*hi[b,n,i]; scale col n by
// hi inv-norm at store (lo pre-normalized). 4 waves as 2x2, wave tile 64x64.
__global__ __launch_bounds__(256) void link_mfma_k(const float* __restrict__ ws,
                                                   float* __restrict__ part) {
    int bid = blockIdx.x, tid = threadIdx.x;
    int lk = bid >> 6, b = bid & 63;
    const int K = lk ? 49 : 196;
    const float* lo = ws + (lk ? POOL1_OFF : POOL0_OFF) + (long)b * 128 * K;
    const float* hi = ws + (lk ? CAM2_OFF : CAM1_OFF) + (long)b * 128 * K;
    const float* nrmp = ws + NORM_OFF + lk * 8192 + b * 128;
    int lane = tid & 63, wv = tid >> 6;
    int lm = lane & 15, q = lane >> 4;
    int wm = (wv >> 1) * 64, wn = (wv & 1) * 64;
    f4v acc[4][4] = {};
    for (int kc = 0; kc < K; kc += 32) {
        v8bf af[4], bff[4];
#pragma unroll
        for (int sm = 0; sm < 4; ++sm)
            af[sm] = load_frag8(lo + (long)(wm + sm * 16 + lm) * K, kc + q * 8, K);
#pragma unroll
        for (int sn = 0; sn < 4; ++sn)
            bff[sn] = load_frag8(hi + (long)(wn + sn * 16 + lm) * K, kc + q * 8, K);
#pragma unroll
        for (int sm = 0; sm < 4; ++sm)
#pragma unroll
            for (int sn = 0; sn < 4; ++sn)
                acc[sm][sn] = __builtin_amdgcn_mfma_f32_16x16x32_bf16(
                    af[sm], bff[sn], acc[sm][sn], 0, 0, 0);
    }
    float* dstb = part + lk * 1048576 + b * 16384;
#pragma unroll
    for (int sn = 0; sn < 4; ++sn) {
        int n = wn + sn * 16 + lm;
        float sh = nrmp[n];
#pragma unroll
        for (int sm = 0; sm < 4; ++sm) {
#pragma unroll
            for (int reg = 0; reg < 4; ++reg) {
                int m = wm + sm * 16 + q * 4 + reg;
                dstb[m * 128 + n] = acc[sm][sn][reg] * sh;
            }
        }
    }
}

// ---------------- reduce partials over b, scale by 1/B ---------------------
__global__ void linkred_k(const float* __restrict__ part, float* __restrict__ out) {
    int id = blockIdx.x * 256 + threadIdx.x;  // < 32768
    int lk = id >> 14, mn = id & 16383;
    const float* p = part + lk * 1048576 + mn;
    float s = 0.f;
#pragma unroll 8
    for (int b = 0; b < 64; ++b) s += p[b * 16384];
    out[49152 + lk * 16384 + mn] = s * (1.0f / 64.0f);
}

extern "C" void kernel_launch(void* const* d_in, const int* in_sizes, int n_in,
                              void* d_out, int out_size, void* d_ws, size_t ws_size,
                              hipStream_t stream) {
    const float* f0 = (const float*)d_in[0];
    const float* w0 = (const float*)d_in[1];
    const float* b0 = (const float*)d_in[2];
    const float* f1 = (const float*)d_in[3];
    const float* w1 = (const float*)d_in[4];
    const float* b1 = (const float*)d_in[5];
    const float* f2 = (const float*)d_in[6];
    const float* w2 = (const float*)d_in[7];
    const float* b2 = (const float*)d_in[8];
    float* ws = (float*)d_ws;
    float* out = (float*)d_out;
    bf16* wb = (bf16*)(ws + WB_OFF);

    prep_w<<<1792, 256, 0, stream>>>(w0, w1, w2, wb);
    cam_gemm<<<1152, 256, 0, stream>>>(f0, f1, f2, wb, ws);
    post_k<<<6144, 256, 0, stream>>>(ws, b0, b1, b2, out);
    link_mfma_k<<<128, 256, 0, stream>>>(ws, ws + PART_OFF);
    linkred_k<<<128, 256, 0, stream>>>(ws + PART_OFF, out);
}

// Round 5
// 308.788 us; speedup vs baseline: 1.1538x; 1.0714x over previous
//
#include <hip/hip_runtime.h>
#include <stdint.h>

#define R 128
#define NB 64

// workspace float offsets
#define CAM0_OFF 0          // 64*128*784 = 6422528
#define CAM1_OFF 6422528    // 64*128*196 = 1605632
#define CAM2_OFF 8028160    // 64*128*49  = 401408
#define POOL0_OFF 8429568   // 1605632
#define POOL1_OFF 10035200  // 401408
#define WB_OFF    10436608  // 458752 bf16 = 229376 float slots
#define PART_OFF  10665984  // 2*16384*64 = 2097152  (layout [lk][m*128+n][b])
#define NORM_OFF  12763136  // 2*8192 inv-norms (cam1 rows, cam2 rows)
// total 12779520 floats ~= 48.8 MiB

typedef __bf16 bf16;
typedef bf16 v2bf __attribute__((ext_vector_type(2)));
typedef bf16 v8bf __attribute__((ext_vector_type(8)));
typedef float f4v __attribute__((ext_vector_type(4)));

// lgkm-only barrier: keeps global loads in flight across the barrier
#define ASM_BARRIER() asm volatile("s_waitcnt lgkmcnt(0)\n\ts_barrier" ::: "memory")

// ---------------- prep: w fp32 -> bf16 (row-major, levels concatenated) -----
__global__ void prep_w(const float* __restrict__ w0, const float* __restrict__ w1,
                       const float* __restrict__ w2, bf16* __restrict__ wb) {
    int id = blockIdx.x * 256 + threadIdx.x;   // < 458752 exact
    float v;
    if (id < 65536)       v = w0[id];
    else if (id < 196608) v = w1[id - 65536];
    else                  v = w2[id - 196608];
    wb[id] = (bf16)v;
}

// ---------------- cam GEMM: cam[b,r,i] = sum_c w[r,c]*fmap[b,c,i] ----------
// 512 threads (8 waves of 32m x 32n), BM=128 BN=64 BK=64.
// Double-buffered LDS + depth-2 register prefetch + one lgkm-only barrier
// per K-iter: loads for tiles t+1,t+2 stay in flight across barriers.
__global__ __launch_bounds__(512) void cam_gemm(
    const float* __restrict__ f0, const float* __restrict__ f1,
    const float* __restrict__ f2, const bf16* __restrict__ wb,
    float* __restrict__ ws) {
    __shared__ bf16 ldsB[2][64 * 72];   // [buf][n][k] bf16, row 144 B

    int bid = blockIdx.x, tid = threadIdx.x;
    int lvl, b, i0;
    if (bid < 64)       { lvl = 2; b = bid; i0 = 0; }              // heavy first
    else if (bid < 320) { int t = bid - 64; lvl = 1; b = t >> 2;
                          int ti = t & 3; i0 = ti < 3 ? ti * 64 : 132; }
    else                { int t = bid - 320; lvl = 0; b = t / 13;
                          int ti = t - b * 13; i0 = ti < 12 ? ti * 64 : 720; }
    const int C  = (lvl == 0) ? 512 : (lvl == 1) ? 1024 : 2048;
    const int HW = (lvl == 0) ? 784 : (lvl == 1) ? 196  : 49;
    const float* fmap = (lvl == 0) ? f0 : (lvl == 1) ? f1 : f2;
    const bf16*  wbl  = wb + ((lvl == 0) ? 0 : (lvl == 1) ? 65536 : 196608);
    float* cam = ws + ((lvl == 0) ? CAM0_OFF : (lvl == 1) ? CAM1_OFF : CAM2_OFF);

    // staging decode: 1 unit/thread; unit = 2 k-rows x 4 i
    int d = tid >> 4;                 // k-pair id 0..31
    int ku2 = d * 2;
    int i4 = (tid & 15) * 4;
    int gbase = b * C * HW + ku2 * HW + i0 + i4;
    int ldsd[4];
    int i4c[4];
#pragma unroll
    for (int e = 0; e < 4; ++e) {
        int i = i4 + e;               // LDS row (n-local)
        int grp = (d >> 2) ^ ((i >> 3) & 7);
        ldsd[e] = i * 72 + grp * 8 + (d & 3) * 2;   // bf16 units
        i4c[e] = min(i, 48);          // clamp for HW==49 path
    }
    const int lane = tid & 63, wave = tid >> 6;
    const int lm = lane & 15, q = lane >> 4;
    const int wm = (wave >> 1) * 32, wn = (wave & 1) * 32;
    int irow[2], ixor[2];
#pragma unroll
    for (int sn = 0; sn < 2; ++sn) {
        irow[sn] = wn + sn * 16 + lm;
        ixor[sn] = (irow[sn] >> 3) & 7;
    }
    const bf16* arow[2];
#pragma unroll
    for (int sm = 0; sm < 2; ++sm)
        arow[sm] = wbl + (wm + sm * 16 + lm) * C + q * 8;

    auto loadT = [&](int kc, float4 (&r)[2]) {
        if (HW != 49) {
            const float* p = fmap + gbase + kc * HW;
            r[0] = *(const float4*)p;
            r[1] = *(const float4*)(p + HW);
        } else {
            const float* p = fmap + b * C * 49 + (kc + ku2) * 49;
            r[0].x = p[i4c[0]]; r[0].y = p[i4c[1]];
            r[0].z = p[i4c[2]]; r[0].w = p[i4c[3]];
            r[1].x = p[49 + i4c[0]]; r[1].y = p[49 + i4c[1]];
            r[1].z = p[49 + i4c[2]]; r[1].w = p[49 + i4c[3]];
        }
    };
    auto stage = [&](float4 (&r)[2], bf16* buf) {
        v2bf t0 = { (bf16)r[0].x, (bf16)r[1].x };
        v2bf t1 = { (bf16)r[0].y, (bf16)r[1].y };
        v2bf t2 = { (bf16)r[0].z, (bf16)r[1].z };
        v2bf t3 = { (bf16)r[0].w, (bf16)r[1].w };
        *(v2bf*)&buf[ldsd[0]] = t0;
        *(v2bf*)&buf[ldsd[1]] = t1;
        *(v2bf*)&buf[ldsd[2]] = t2;
        *(v2bf*)&buf[ldsd[3]] = t3;
    };

    f4v acc[2][2] = {};
    auto comp = [&](int kc, const bf16* buf) {
#pragma unroll
        for (int ks = 0; ks < 64; ks += 32) {
            v8bf af[2];
#pragma unroll
            for (int sm = 0; sm < 2; ++sm)
                af[sm] = *(const v8bf*)(arow[sm] + kc + ks);
            v8bf bfr[2];
#pragma unroll
            for (int sn = 0; sn < 2; ++sn) {
                int grp = (q + ((ks >> 5) << 2)) ^ ixor[sn];
                bfr[sn] = *(const v8bf*)&buf[irow[sn] * 72 + grp * 8];
            }
#pragma unroll
            for (int sm = 0; sm < 2; ++sm)
#pragma unroll
                for (int sn = 0; sn < 2; ++sn)
                    acc[sm][sn] = __builtin_amdgcn_mfma_f32_16x16x32_bf16(
                        af[sm], bfr[sn], acc[sm][sn], 0, 0, 0);
        }
    };

    const int nIter = C >> 6;       // 8 / 16 / 32, always even
    float4 rA[2], rB[2];
    loadT(0, rA);
    loadT(64, rB);
    for (int t = 0; t < nIter; t += 2) {
        stage(rA, ldsB[0]);          // waits rA only (vmcnt keeps rB flying)
        ASM_BARRIER();
        if (t + 2 < nIter) loadT((t + 2) << 6, rA);
        comp(t << 6, ldsB[0]);
        stage(rB, ldsB[1]);
        ASM_BARRIER();
        if (t + 3 < nIter) loadT((t + 3) << 6, rB);
        comp((t + 1) << 6, ldsB[1]);
    }
    // epilogue: D row = q*4+reg, col = lm
#pragma unroll
    for (int sn = 0; sn < 2; ++sn) {
        int i_n = i0 + irow[sn];
        if (i_n < HW) {
            int base = (b * R) * HW + i_n;
#pragma unroll
            for (int sm = 0; sm < 2; ++sm) {
#pragma unroll
                for (int reg = 0; reg < 4; ++reg) {
                    int r = wm + sm * 16 + q * 4 + reg;
                    cam[base + r * HW] = acc[sm][sn][reg];
                }
            }
        }
    }
}

// ---------------- fused post: stats + inv-norms + pooling (single cam read) -
__global__ __launch_bounds__(256) void post_k(
    float* __restrict__ ws, const float* __restrict__ b0,
    const float* __restrict__ b1, const float* __restrict__ b2,
    float* __restrict__ out) {
    __shared__ float plds[4 * 784];
    int gw = blockIdx.x * 4 + (threadIdx.x >> 6);  // < 24576
    int lane = threadIdx.x & 63;
    float* myl = plds + (threadIdx.x >> 6) * 784;
    int lvl = gw >> 13, row = gw & 8191;           // row = b*128 + r
    const int HW = (lvl == 0) ? 784 : (lvl == 1) ? 196 : 49;
    const float* cam = ws + ((lvl == 0) ? CAM0_OFF : (lvl == 1) ? CAM1_OFF : CAM2_OFF)
                        + (long)row * HW;
    float s = 0.f, ss = 0.f;
    for (int j = lane; j < HW; j += 64) {
        float v = cam[j]; s += v; ss += v * v; myl[j] = v;
    }
#pragma unroll
    for (int o = 32; o; o >>= 1) { s += __shfl_xor(s, o); ss += __shfl_xor(ss, o); }
    if (lane == 0) {
        const float* bias = (lvl == 0) ? b0 : (lvl == 1) ? b1 : b2;
        float mean = s / (float)HW;
        out[lvl * 8192 + row] = mean + bias[row & 127];
        float var = fmaxf(ss - s * mean, 0.f) / (float)(HW - 1);
        out[24576 + lvl * 8192 + row] = sqrtf(var);
        if (lvl >= 1)
            ws[NORM_OFF + (lvl - 1) * 8192 + row] = 1.0f / fmaxf(sqrtf(ss), 1e-12f);
    }
    if (lvl <= 1) {
        const int OP = (lvl == 0) ? 196 : 49;
        const int OW = (lvl == 0) ? 14 : 7;
        const int IW = (lvl == 0) ? 28 : 14;
        float vals[4]; float ssp = 0.f; int cnt = 0;
        for (int p = lane; p < OP; p += 64) {
            int oh = p / OW, ow = p - oh * OW;
            int i0 = oh * 2 * IW + ow * 2;
            float v = (myl[i0] + myl[i0 + 1] + myl[i0 + IW] + myl[i0 + IW + 1]) * 0.25f;
            vals[cnt++] = v; ssp += v * v;
        }
#pragma unroll
        for (int o = 32; o; o >>= 1) ssp += __shfl_xor(ssp, o);
        float inv = 1.0f / fmaxf(sqrtf(ssp), 1e-12f);
        float* dst = ws + ((lvl == 0) ? POOL0_OFF : POOL1_OFF) + (long)row * OP;
        cnt = 0;
        for (int p = lane; p < OP; p += 64) dst[p] = vals[cnt++] * inv;
    }
}

// ---------------- link via MFMA, direct global frags (contraction over i) ---
__device__ inline v8bf load_frag8(const float* __restrict__ row, int k0, int K) {
    v8bf f;
    if (k0 + 8 <= K && (K & 3) == 0) {
        float4 a = *(const float4*)(row + k0);
        float4 c = *(const float4*)(row + k0 + 4);
        f[0] = (bf16)a.x; f[1] = (bf16)a.y; f[2] = (bf16)a.z; f[3] = (bf16)a.w;
        f[4] = (bf16)c.x; f[5] = (bf16)c.y; f[6] = (bf16)c.z; f[7] = (bf16)c.w;
    } else {
#pragma unroll
        for (int j = 0; j < 8; ++j)
            f[j] = (k0 + j < K) ? (bf16)row[k0 + j] : (bf16)0.f;
    }
    return f;
}

// block per (lk, b, m-half): 64m x 128n. Partials stored [lk][m*128+n][b]
// (contiguous-b) so the reducer reads dense runs. hi inv-norm applied here.
__global__ __launch_bounds__(256) void link_mfma_k(const float* __restrict__ ws,
                                                   float* __restrict__ part) {
    int bid = blockIdx.x, tid = threadIdx.x;
    int lk = bid >> 7, rem = bid & 127;
    int b = rem >> 1, mh = rem & 1;
    const int K = lk ? 49 : 196;
    const float* lo = ws + (lk ? POOL1_OFF : POOL0_OFF) + (long)(b * 128 + mh * 64) * K;
    const float* hi = ws + (lk ? CAM2_OFF : CAM1_OFF) + (long)b * 128 * K;
    const float* nrmp = ws + NORM_OFF + lk * 8192 + b * 128;
    int lane = tid & 63, wv = tid >> 6;
    int lm = lane & 15, q = lane >> 4;
    int wm = (wv >> 1) * 32, wn = (wv & 1) * 64;
    f4v acc[2][4] = {};
    for (int kc = 0; kc < K; kc += 32) {
        v8bf af[2], bff[4];
#pragma unroll
        for (int sm = 0; sm < 2; ++sm)
            af[sm] = load_frag8(lo + (long)(wm + sm * 16 + lm) * K, kc + q * 8, K);
#pragma unroll
        for (int sn = 0; sn < 4; ++sn)
            bff[sn] = load_frag8(hi + (long)(wn + sn * 16 + lm) * K, kc + q * 8, K);
#pragma unroll
        for (int sm = 0; sm < 2; ++sm)
#pragma unroll
            for (int sn = 0; sn < 4; ++sn)
                acc[sm][sn] = __builtin_amdgcn_mfma_f32_16x16x32_bf16(
                    af[sm], bff[sn], acc[sm][sn], 0, 0, 0);
    }
#pragma unroll
    for (int sn = 0; sn < 4; ++sn) {
        int n = wn + sn * 16 + lm;
        float sh = nrmp[n];
#pragma unroll
        for (int sm = 0; sm < 2; ++sm) {
#pragma unroll
            for (int reg = 0; reg < 4; ++reg) {
                int m = mh * 64 + wm + sm * 16 + q * 4 + reg;
                part[(long)(lk * 16384 + m * 128 + n) * 64 + b] = acc[sm][sn][reg] * sh;
            }
        }
    }
}

// ---------------- reduce partials over b (contiguous), scale by 1/B --------
__global__ void linkred_k(const float* __restrict__ part, float* __restrict__ out) {
    int id = blockIdx.x * 256 + threadIdx.x;  // < 32768 = 2*16384
    const float* p = part + (long)id * 64;
    float s = 0.f;
#pragma unroll
    for (int j = 0; j < 16; ++j) {
        float4 v = *(const float4*)(p + j * 4);
        s += v.x + v.y + v.z + v.w;
    }
    out[49152 + id] = s * (1.0f / 64.0f);
}

extern "C" void kernel_launch(void* const* d_in, const int* in_sizes, int n_in,
                              void* d_out, int out_size, void* d_ws, size_t ws_size,
                              hipStream_t stream) {
    const float* f0 = (const float*)d_in[0];
    const float* w0 = (const float*)d_in[1];
    const float* b0 = (const float*)d_in[2];
    const float* f1 = (const float*)d_in[3];
    const float* w1 = (const float*)d_in[4];
    const float* b1 = (const float*)d_in[5];
    const float* f2 = (const float*)d_in[6];
    const float* w2 = (const float*)d_in[7];
    const float* b2 = (const float*)d_in[8];
    float* ws = (float*)d_ws;
    float* out = (float*)d_out;
    bf16* wb = (bf16*)(ws + WB_OFF);

    prep_w<<<1792, 256, 0, stream>>>(w0, w1, w2, wb);
    cam_gemm<<<1152, 512, 0, stream>>>(f0, f1, f2, wb, ws);
    post_k<<<6144, 256, 0, stream>>>(ws, b0, b1, b2, out);
    link_mfma_k<<<256, 256, 0, stream>>>(ws, ws + PART_OFF);
    linkred_k<<<128, 256, 0, stream>>>(ws + PART_OFF, out);
}